// Round 5
// baseline (509.441 us; speedup 1.0000x reference)
//
#include <hip/hip_runtime.h>
#include <math.h>
#include <stdint.h>
#include <stddef.h>

// ---------------------------------------------------------------------------
// Attention layer for MI355X (gfx950). I/O fp32; internal bf16 MFMA pipeline.
//   cvt_all: x/wq/wk/wv/wo -> bf16 (single fused launch)
//   qkv_proj4: BM=128 x BN=384 4-phase counted-vmcnt GEMM over virtual
//       B=[wq;wk;wv] -> grid 256 = perfect CU fill, T2 swizzle, T1 XCD map
//   oproj8: 128x256 4-phase counted-vmcnt GEMM (T2+T5), XCD map
//   rope_all: RoPE(Q)+RoPE(K) fused
//   flash_attn: LDS-staged (async global_load_lds, double-buffered),
//               key-permuted S^T trick, causal, GQA rep=4, defer-max rescale
// Only mfma_f32_16x16x32_bf16 is used (HW-verified layouts m89/m97).
// ---------------------------------------------------------------------------

typedef __attribute__((ext_vector_type(8))) short bf16x8;
typedef __attribute__((ext_vector_type(4))) short bf16x4;
typedef __attribute__((ext_vector_type(4))) float f32x4;
typedef unsigned short u16;

#define NEG_BIG (-1.0e9f)
#define MFMA32(a, b, c) __builtin_amdgcn_mfma_f32_16x16x32_bf16(a, b, c, 0, 0, 0)

__device__ __forceinline__ float bf2f(u16 b) {
    return __uint_as_float(((unsigned int)b) << 16);
}
__device__ __forceinline__ u16 f2bf(float f) {
    unsigned int u = __float_as_uint(f);
    u += 0x7fff + ((u >> 16) & 1);   // RNE
    return (u16)(u >> 16);
}
__device__ __forceinline__ void gld_lds16(short* lds, const u16* g) {
    __builtin_amdgcn_global_load_lds(
        (const __attribute__((address_space(1))) void*)g,
        (__attribute__((address_space(3))) void*)lds, 16, 0, 0);
}

// ---------------------------------------------------------------------------
// fused fp32 -> bf16 convert for all 5 tensors (one launch)
// blocks: x 4096 | wq 8192 | wk 2048 | wv 2048 | wo 8192  (2048 elem/block)
// ---------------------------------------------------------------------------
__global__ __launch_bounds__(256) void cvt_all(
    const float* __restrict__ x, const float* __restrict__ wq,
    const float* __restrict__ wk, const float* __restrict__ wv,
    const float* __restrict__ wo,
    u16* __restrict__ xb, u16* __restrict__ wqb, u16* __restrict__ wkb,
    u16* __restrict__ wvb, u16* __restrict__ wob) {
    const int b = blockIdx.x;
    const float* s; u16* d; int off;
    if (b < 4096)       { s = x;  d = xb;  off = b; }
    else if (b < 12288) { s = wq; d = wqb; off = b - 4096; }
    else if (b < 14336) { s = wk; d = wkb; off = b - 12288; }
    else if (b < 16384) { s = wv; d = wvb; off = b - 14336; }
    else                { s = wo; d = wob; off = b - 16384; }
    const int i = off * 2048 + threadIdx.x * 8;
    float4 a, c;
    __builtin_memcpy(&a, s + i, 16);
    __builtin_memcpy(&c, s + i + 4, 16);
    bf16x8 o;
    o[0] = (short)f2bf(a.x); o[1] = (short)f2bf(a.y);
    o[2] = (short)f2bf(a.z); o[3] = (short)f2bf(a.w);
    o[4] = (short)f2bf(c.x); o[5] = (short)f2bf(c.y);
    o[6] = (short)f2bf(c.z); o[7] = (short)f2bf(c.w);
    __builtin_memcpy(d + i, &o, 16);
}

// ---------------------------------------------------------------------------
// qkv_proj4: C = x[2048,4096] @ W^T where W = [wq;wk;wv] (6144 rows).
// BM=128, BN=384, BK=64, 512 threads (8 waves as 2M x 4N; per-wave 64x96).
// Grid 256 blocks = perfect fill. 4 phases/iter (2 K-tiles), one half-tile
// stage (1 A-round + 3 B-rounds = 4 gld_lds16) per phase, 3 stages in
// flight -> vmcnt(8) steady, peel 8/4/0. T2 swizzle identical to r4
// (verified): read slot quad ^ ((row>>1)&3); inverse baked into the global
// source slot cs = (t&3)^((t>>3)&3). Epilogue routes cols to Q/Kc/Vt.
// ---------------------------------------------------------------------------

#define Q4_STGA(bf_, ks_, kt_)                                               \
    gld_lds16(Ad + (bf_) * 8192 + (ks_) * 4096,                              \
              Ag + (size_t)(kt_) * 64 + (ks_) * 32);
#define Q4_STGB(bf_, ks_, kt_)                                               \
    {                                                                        \
        _Pragma("unroll") for (int r_ = 0; r_ < 3; ++r_)                     \
            gld_lds16(Bd + (bf_) * 24576 + (ks_) * 12288 + r_ * 4096,        \
                      Bgr[r_] + (size_t)(kt_) * 64 + (ks_) * 32);            \
    }
#define Q4_STG(bf_, ks_, kt_) { Q4_STGA(bf_, ks_, kt_); Q4_STGB(bf_, ks_, kt_); }

#define Q4_PHASE(bf_, ks_, STAGE_, WAIT_)                                    \
    {                                                                        \
        _Pragma("unroll") for (int n_ = 0; n_ < 6; ++n_)                     \
            __builtin_memcpy(&bfr[n_], Bs + (bf_) * 24576 + (ks_) * 12288 +  \
                                           bbase + n_ * 512, 16);            \
        _Pragma("unroll") for (int i_ = 0; i_ < 4; ++i_)                     \
            __builtin_memcpy(&af[i_], S + (bf_) * 8192 + (ks_) * 4096 +      \
                                          abase + i_ * 512, 16);             \
        STAGE_;                                                              \
        __builtin_amdgcn_s_barrier();                                        \
        asm volatile("s_waitcnt lgkmcnt(0)" ::: "memory");                   \
        __builtin_amdgcn_s_setprio(1);                                       \
        _Pragma("unroll") for (int i_ = 0; i_ < 4; ++i_)                     \
            _Pragma("unroll") for (int n_ = 0; n_ < 6; ++n_)                 \
                acc[i_][n_] = MFMA32(af[i_], bfr[n_], acc[i_][n_]);          \
        __builtin_amdgcn_s_setprio(0);                                       \
        WAIT_;                                                               \
        __builtin_amdgcn_s_barrier();                                        \
    }

__global__ __launch_bounds__(512, 2) void qkv_proj4(
    const u16* __restrict__ x,
    const u16* __restrict__ wq, const u16* __restrict__ wk,
    const u16* __restrict__ wv,
    u16* __restrict__ Q, u16* __restrict__ Kc, u16* __restrict__ Vt) {
    __shared__ __align__(16) short S[65536];   // A: 2x8192, B: 2x24576
    short* const Bs = S + 16384;

    // T1: XCD-chunked bijective map (256 = 8 XCDs x 32). logical = nb*16+mb
    // so each XCD owns 2 full B-panels' worth of blocks.
    const int lid = blockIdx.x;
    const int logical = (lid & 7) * 32 + (lid >> 3);
    const int mb = logical & 15, nb = logical >> 4;

    const int t = threadIdx.x;
    const int lane = t & 63, l15 = lane & 15, quad = lane >> 4;
    const int wid = t >> 6, wr = wid >> 2, wc = wid & 3;

    // staging sources: thread t covers row t>>2 (A) / virtual row
    // nb*384 + 128r + (t>>2) (B round r); global slot cs (inv. swizzle)
    const int srow = t >> 2;
    const int cs = (t & 3) ^ ((t >> 3) & 3);
    const u16* const Ag = x + (size_t)(mb * 128 + srow) * 4096 + cs * 8;
    const u16* Bgr[3];
#pragma unroll
    for (int r = 0; r < 3; ++r) {
        const int chunk = nb * 3 + r;   // 128-row chunk of [wq;wk;wv]
        const u16* base; int lrow;
        if (chunk < 32)      { base = wq; lrow = chunk * 128; }
        else if (chunk < 40) { base = wk; lrow = (chunk - 32) * 128; }
        else                 { base = wv; lrow = (chunk - 40) * 128; }
        Bgr[r] = base + (size_t)(lrow + srow) * 4096 + cs * 8;
    }
    short* const Ad = S + t * 8;
    short* const Bd = Bs + t * 8;

    // ds-read bases, T2-swizzled slot
    const int swz = (quad ^ ((l15 >> 1) & 3)) * 8;
    const int abase = (wr * 64 + l15) * 32 + swz;
    const int bbase = (wc * 96 + l15) * 32 + swz;

    f32x4 acc[4][6] = {};
    bf16x8 af[4], bfr[6];

    // prologue: 3 half-stages
    Q4_STG(0, 0, 0); Q4_STG(0, 1, 0); Q4_STG(1, 0, 1);
    asm volatile("s_waitcnt vmcnt(8)" ::: "memory");
    __builtin_amdgcn_s_barrier();

    const int nIt = 32;   // K=4096, 2 K-tiles (BK=64) per iteration
    for (int it = 0; it < nIt; ++it) {
        const int k0 = 2 * it, k1 = k0 + 1;
        const bool nl = (it < nIt - 1);
        Q4_PHASE(0, 0, Q4_STG(1, 1, k1),
                 asm volatile("s_waitcnt vmcnt(8)" ::: "memory"));
        Q4_PHASE(0, 1, if (nl) Q4_STG(0, 0, k0 + 2),
                 if (nl) { asm volatile("s_waitcnt vmcnt(8)" ::: "memory"); }
                 else    { asm volatile("s_waitcnt vmcnt(4)" ::: "memory"); });
        Q4_PHASE(1, 0, if (nl) Q4_STG(0, 1, k0 + 2),
                 if (nl) { asm volatile("s_waitcnt vmcnt(8)" ::: "memory"); }
                 else    { asm volatile("s_waitcnt vmcnt(0)" ::: "memory"); });
        Q4_PHASE(1, 1, if (nl) Q4_STG(1, 0, k1 + 2),
                 if (nl) { asm volatile("s_waitcnt vmcnt(8)" ::: "memory"); });
    }

    // epilogue: C/D layout col=l15, row=quad*4+r; route cols to Q/Kc/Vt
#pragma unroll
    for (int i = 0; i < 4; ++i) {
        const int rowb = mb * 128 + wr * 64 + i * 16 + quad * 4;
#pragma unroll
        for (int j = 0; j < 6; ++j) {
            const int colb = nb * 384 + wc * 96 + j * 16;   // wave-uniform
            const int col = colb + l15;
            if (colb < 4096) {
#pragma unroll
                for (int r = 0; r < 4; ++r)
                    Q[(size_t)(rowb + r) * 4096 + col] = f2bf(acc[i][j][r]);
            } else if (colb < 5120) {
#pragma unroll
                for (int r = 0; r < 4; ++r)
                    Kc[(size_t)(rowb + r) * 1024 + (col - 4096)] =
                        f2bf(acc[i][j][r]);
            } else {
                bf16x4 v;
#pragma unroll
                for (int r = 0; r < 4; ++r) v[r] = (short)f2bf(acc[i][j][r]);
                __builtin_memcpy(Vt + (size_t)(col - 5120) * 2048 + rowb,
                                 &v, 8);
            }
        }
    }
}

// ---------------------------------------------------------------------------
// oproj: 4-phase counted-vmcnt GEMM, BM=128 BN=256, fp32 out. (r3 structure,
// r4 T2 swizzle, + T1 XCD map.) 512 threads, grid 256 1-D.
// ---------------------------------------------------------------------------

#define G8_STGA(bf_, ks_, kt_)                                               \
    gld_lds16(Ad + (bf_) * 8192 + (ks_) * 4096,                              \
              Ag + (size_t)(kt_) * 64 + (ks_) * 32);
#define G8_STGB(bf_, ks_, kt_)                                               \
    {                                                                        \
        _Pragma("unroll") for (int r_ = 0; r_ < 2; ++r_)                     \
            gld_lds16(Bd + (bf_) * 16384 + (ks_) * 8192 + r_ * 4096,         \
                      Bg + gK * r_ + (size_t)(kt_) * 64 + (ks_) * 32);       \
    }
#define G8_PHASE(bf_, ks_, STAGE_, WAIT_)                                    \
    {                                                                        \
        _Pragma("unroll") for (int n_ = 0; n_ < 4; ++n_)                     \
            __builtin_memcpy(&bfr[n_], Bs + (bf_) * 16384 + (ks_) * 8192 +   \
                                           bbase + n_ * 512, 16);            \
        _Pragma("unroll") for (int i_ = 0; i_ < 4; ++i_)                     \
            __builtin_memcpy(&af[i_], S + (bf_) * 8192 + (ks_) * 4096 +      \
                                          abase + i_ * 512, 16);             \
        STAGE_;                                                              \
        __builtin_amdgcn_s_barrier();                                        \
        asm volatile("s_waitcnt lgkmcnt(0)" ::: "memory");                   \
        __builtin_amdgcn_s_setprio(1);                                       \
        _Pragma("unroll") for (int i_ = 0; i_ < 4; ++i_)                     \
            _Pragma("unroll") for (int n_ = 0; n_ < 4; ++n_)                 \
                acc[i_][n_] = MFMA32(af[i_], bfr[n_], acc[i_][n_]);          \
        __builtin_amdgcn_s_setprio(0);                                       \
        WAIT_;                                                               \
        __builtin_amdgcn_s_barrier();                                        \
    }

__global__ __launch_bounds__(512, 2) void oproj8(
    const u16* __restrict__ A, const u16* __restrict__ wo,
    float* __restrict__ out) {
    __shared__ __align__(16) short S[49152];   // A: 2x8192, B: 2x16384
    short* const Bs = S + 16384;

    const int lid = blockIdx.x;
    const int logical = (lid & 7) * 32 + (lid >> 3);
    const int mb = logical & 15, nb = logical >> 4;

    const int t = threadIdx.x;
    const int lane = t & 63, l15 = lane & 15, quad = lane >> 4;
    const int wid = t >> 6, wr = wid >> 2, wc = wid & 3;

    const int srow = t >> 2;
    const int cs = (t & 3) ^ ((t >> 3) & 3);
    const u16* const Ag = A + (size_t)(mb * 128 + srow) * 4096 + cs * 8;
    const u16* const Bg = wo + (size_t)(nb * 256 + srow) * 4096 + cs * 8;
    short* const Ad = S + t * 8;
    short* const Bd = Bs + t * 8;
    const size_t gK = (size_t)128 * 4096;

    const int swz = (quad ^ ((l15 >> 1) & 3)) * 8;
    const int abase = (wr * 64 + l15) * 32 + swz;
    const int bbase = (wc * 64 + l15) * 32 + swz;

    f32x4 acc[4][4] = {};
    bf16x8 af[4], bfr[4];

    // prologue: 3 half-stages of 3 loads each (1 A + 2 B)
    G8_STGA(0, 0, 0); G8_STGB(0, 0, 0);
    G8_STGA(0, 1, 0); G8_STGB(0, 1, 0);
    G8_STGA(1, 0, 1); G8_STGB(1, 0, 1);
    asm volatile("s_waitcnt vmcnt(6)" ::: "memory");
    __builtin_amdgcn_s_barrier();

    const int nIt = 32;
    for (int it = 0; it < nIt; ++it) {
        const int k0 = 2 * it, k1 = k0 + 1;
        const bool nl = (it < nIt - 1);
        G8_PHASE(0, 0, { G8_STGA(1, 1, k1); G8_STGB(1, 1, k1); },
                 asm volatile("s_waitcnt vmcnt(6)" ::: "memory"));
        G8_PHASE(0, 1, if (nl) { G8_STGA(0, 0, k0 + 2); G8_STGB(0, 0, k0 + 2); },
                 if (nl) { asm volatile("s_waitcnt vmcnt(6)" ::: "memory"); }
                 else    { asm volatile("s_waitcnt vmcnt(3)" ::: "memory"); });
        G8_PHASE(1, 0, if (nl) { G8_STGA(0, 1, k0 + 2); G8_STGB(0, 1, k0 + 2); },
                 if (nl) { asm volatile("s_waitcnt vmcnt(6)" ::: "memory"); }
                 else    { asm volatile("s_waitcnt vmcnt(0)" ::: "memory"); });
        G8_PHASE(1, 1, if (nl) { G8_STGA(1, 0, k1 + 2); G8_STGB(1, 0, k1 + 2); },
                 if (nl) { asm volatile("s_waitcnt vmcnt(6)" ::: "memory"); });
    }

#pragma unroll
    for (int i = 0; i < 4; ++i) {
        const int rowb = mb * 128 + wr * 64 + i * 16 + quad * 4;
#pragma unroll
        for (int j = 0; j < 4; ++j) {
            const int col = nb * 256 + wc * 64 + j * 16 + l15;
#pragma unroll
            for (int r = 0; r < 4; ++r)
                out[(size_t)(rowb + r) * 4096 + col] = acc[i][j][r];
        }
    }
}

// ---------------------------------------------------------------------------
// fused RoPE: Q (32 heads) + Kc (8 heads) in one launch.
// idx -> pair i (0..63), head hh (0..39), seq s. hh<32 -> Q else K.
// ---------------------------------------------------------------------------
__global__ __launch_bounds__(256) void rope_all(
    u16* __restrict__ Q, u16* __restrict__ Kc,
    const float* __restrict__ cosb, const float* __restrict__ sinb) {
    const int idx = blockIdx.x * blockDim.x + threadIdx.x;
    const int i = idx & 63;
    const int hh = (idx >> 6) % 40;
    const int s = (idx >> 6) / 40;
    u16* p;
    if (hh < 32)
        p = Q + (size_t)s * 4096 + hh * 128 + 2 * i;
    else
        p = Kc + (size_t)s * 1024 + (hh - 32) * 128 + 2 * i;
    const float x0 = bf2f(p[0]), x1 = bf2f(p[1]);
    const float c = cosb[s * 64 + i], sn = sinb[s * 64 + i];
    p[0] = f2bf(x0 * c - x1 * sn);
    p[1] = f2bf(x0 * sn + x1 * c);
}

// ---------------------------------------------------------------------------
// Flash attention, LDS-staged (2-phase global_load_lds pipeline, dbuf).
// K tile [32 keys][128 dims] XOR-swizzled 16B slots (2-way, free);
// V tile [128 feats][32 keys] with T2 slot swizzle quad ^ ((row>>1)&3).
// Key-permuted S^T trick; online softmax with defer-max THR=8.
// ---------------------------------------------------------------------------
__device__ __forceinline__ int kswz(int row, int cs) {
    int f = (row & 3) | ((row & 8) >> 1);
    return row * 128 + ((cs ^ f) << 3);
}

template <bool MASKED>
__device__ __forceinline__ void fa_step_lds(
    const short* __restrict__ Kl, const short* __restrict__ Vl,
    int kb, int q0, int l15, int quad,
    const int (&koff)[8], const int (&voff)[8],
    const bf16x8 (&qf)[4], f32x4 (&o)[8], float& m, float& l) {
    const float scale = 0.08838834764831845f;  // 1/sqrt(128)

    // K frags from LDS (swizzled) + S^T = K.Q^T
    bf16x8 kf[8];
#pragma unroll
    for (int i = 0; i < 8; ++i) __builtin_memcpy(&kf[i], Kl + koff[i], 16);
    f32x4 s0 = {0, 0, 0, 0}, s1 = {0, 0, 0, 0};
#pragma unroll
    for (int c = 0; c < 4; ++c) {
        s0 = MFMA32(kf[c], qf[c], s0);
        s1 = MFMA32(kf[4 + c], qf[c], s1);
    }

    // V frags early: ds_read latency hides under softmax
    bf16x8 vf[8];
#pragma unroll
    for (int n = 0; n < 8; ++n) __builtin_memcpy(&vf[n], Vl + voff[n], 16);

    // scale + causal mask. Lane (quad,l15): s0[r] = key kb+8*quad+r,
    // s1[r] = key kb+8*quad+4+r, q column = l15.
    float sv0[4], sv1[4];
    const int q = q0 + l15;
#pragma unroll
    for (int r = 0; r < 4; ++r) {
        sv0[r] = s0[r] * scale;
        sv1[r] = s1[r] * scale;
        if (MASKED) {
            if (kb + 8 * quad + r > q) sv0[r] = NEG_BIG;
            if (kb + 8 * quad + 4 + r > q) sv1[r] = NEG_BIG;
        }
    }

    // online softmax: all 32 keys of q-col l15 spread across quads
    float mx = fmaxf(fmaxf(fmaxf(sv0[0], sv0[1]), fmaxf(sv0[2], sv0[3])),
                     fmaxf(fmaxf(sv1[0], sv1[1]), fmaxf(sv1[2], sv1[3])));
    mx = fmaxf(mx, __shfl_xor(mx, 16));
    mx = fmaxf(mx, __shfl_xor(mx, 32));

    // defer-max: only rescale O when the max grew past the threshold
    float alpha = 1.0f;
    if (!__all(mx <= m + 8.0f)) {
        float mnew = fmaxf(m, mx);
        alpha = __expf(m - mnew);
        float aO[4];
#pragma unroll
        for (int r = 0; r < 4; ++r) aO[r] = __shfl(alpha, quad * 20 + r);
#pragma unroll
        for (int n = 0; n < 8; ++n)
#pragma unroll
            for (int r = 0; r < 4; ++r) o[n][r] *= aO[r];
        m = mnew;
    }

    float p0[4], p1[4], sum = 0.f;
#pragma unroll
    for (int r = 0; r < 4; ++r) {
        p0[r] = __expf(sv0[r] - m);
        p1[r] = __expf(sv1[r] - m);
        sum += p0[r] + p1[r];
    }
    sum += __shfl_xor(sum, 16);
    sum += __shfl_xor(sum, 32);
    l = l * alpha + sum;

    // pack P into the 16x16x32 A-frag: element j = key 8*quad+j (zero move)
    bf16x8 pa;
#pragma unroll
    for (int r = 0; r < 4; ++r) {
        pa[r] = (short)f2bf(p0[r]);
        pa[4 + r] = (short)f2bf(p1[r]);
    }

    // O += P.V
#pragma unroll
    for (int n = 0; n < 8; ++n) o[n] = MFMA32(pa, vf[n], o[n]);
}

__device__ __forceinline__ void fa_task(
    const u16* __restrict__ Q, const u16* __restrict__ Kc,
    const u16* __restrict__ Vt, u16* __restrict__ O,
    short* __restrict__ Kl0, short* __restrict__ Vl0,
    int q0, int nbt, int h, int kvh, int t) {
    const int lane = t & 63;
    const int l15 = lane & 15, quad = lane >> 4;

    // Q B-frags (n=q=l15, k=d chunks)
    bf16x8 qf[4];
    const u16* qp = Q + (size_t)(q0 + l15) * 4096 + h * 128 + quad * 8;
#pragma unroll
    for (int c = 0; c < 4; ++c) __builtin_memcpy(&qf[c], qp + c * 32, 16);

    // ---- staging addresses (per-thread constants) ----
    const u16* ksrc[2]; short* kdst[2];
    const u16* vsrc[2]; short* vdst[2];
#pragma unroll
    for (int r = 0; r < 2; ++r) {
        int row = (t >> 4) + 16 * r;
        int slot = t & 15;
        int f = (row & 3) | ((row & 8) >> 1);
        int cks = slot ^ f;
        ksrc[r] = Kc + (size_t)row * 1024 + kvh * 128 + cks * 8;
        kdst[r] = Kl0 + (t + 256 * r) * 8;
        int rowv = (t >> 2) + 64 * r;
        int csv = (t & 3) ^ ((t >> 3) & 3);   // inverse of V read swizzle
        vsrc[r] = Vt + (size_t)(kvh * 128 + rowv) * 2048 + csv * 8;
        vdst[r] = Vl0 + (t + 256 * r) * 8;
    }

    // ---- LDS read offsets (per-lane constants) ----
    const int rk0 = 8 * (l15 >> 2) + (l15 & 3);   // key-permuted row (s0)
    int koff[8], voff[8];
#pragma unroll
    for (int c = 0; c < 4; ++c) {
        koff[c] = kswz(rk0, quad + c * 4);
        koff[4 + c] = kswz(rk0 + 4, quad + c * 4);
    }
    const int vswz = (quad ^ ((l15 >> 1) & 3)) * 8;
#pragma unroll
    for (int n = 0; n < 8; ++n) voff[n] = (n * 16 + l15) * 32 + vswz;

    f32x4 o[8] = {};
    float m = NEG_BIG, l = 0.f;
    const int my_nb = (q0 + 47) / 32;   // my causal key-block count (<= nbt)

    // ---- prologue: stage block 0 into buffer 0 ----
    {
        gld_lds16(kdst[0], ksrc[0]);
        gld_lds16(kdst[1], ksrc[1]);
        gld_lds16(vdst[0], vsrc[0]);
        gld_lds16(vdst[1], vsrc[1]);
    }
    __syncthreads();

    for (int ib = 0; ib < nbt; ++ib) {
        if (ib + 1 < nbt) {   // stage next block into the other buffer
            int kb = (ib + 1) * 32;
            int bo = ((ib + 1) & 1) * 4096;
            gld_lds16(kdst[0] + bo, ksrc[0] + (size_t)kb * 1024);
            gld_lds16(kdst[1] + bo, ksrc[1] + (size_t)kb * 1024);
            gld_lds16(vdst[0] + bo, vsrc[0] + kb);
            gld_lds16(vdst[1] + bo, vsrc[1] + kb);
        }
        if (ib < my_nb) {   // wave-uniform predicate
            const short* Kl = Kl0 + (ib & 1) * 4096;
            const short* Vl = Vl0 + (ib & 1) * 4096;
            if (ib == my_nb - 1)
                fa_step_lds<true>(Kl, Vl, ib * 32, q0, l15, quad, koff, voff,
                                  qf, o, m, l);
            else
                fa_step_lds<false>(Kl, Vl, ib * 32, q0, l15, quad, koff, voff,
                                   qf, o, m, l);
        }
        __syncthreads();
    }

    // epilogue: O rows are q=quad*4+r; fetch l from q=l15 lanes
    float inv[4];
#pragma unroll
    for (int r = 0; r < 4; ++r) inv[r] = 1.f / __shfl(l, quad * 20 + r);
#pragma unroll
    for (int n = 0; n < 8; ++n)
#pragma unroll
        for (int r = 0; r < 4; ++r) {
            int row = q0 + quad * 4 + r;
            O[(size_t)row * 4096 + h * 128 + n * 16 + l15] =
                f2bf(o[n][r] * inv[r]);
        }
}

__global__ __launch_bounds__(256) void flash_attn(
    const u16* __restrict__ Q, const u16* __restrict__ Kc,
    const u16* __restrict__ Vt, u16* __restrict__ O) {
    __shared__ __align__(16) short Kl[2 * 32 * 128];
    __shared__ __align__(16) short Vl[2 * 128 * 32];
    const int pp = blockIdx.x;   // 0..15  (q-tile pair: pp and 31-pp)
    const int h = blockIdx.y;    // 0..31
    const int kvh = h >> 2;
    const int t = threadIdx.x, wave = t >> 6;
    // wave w of tile pp pairs with wave 3-w of tile 31-pp: 68 lockstep
    // iterations per block, identical for every block (perfect balance)
    fa_task(Q, Kc, Vt, O, Kl, Vl, pp * 64 + wave * 16, 2 * pp + 2, h, kvh, t);
    const int tb = 31 - pp;
    fa_task(Q, Kc, Vt, O, Kl, Vl, tb * 64 + (3 - wave) * 16, 2 * tb + 2, h,
            kvh, t);
}

// ---------------------------------------------------------------------------
extern "C" void kernel_launch(void* const* d_in, const int* in_sizes, int n_in,
                              void* d_out, int out_size, void* d_ws,
                              size_t ws_size, hipStream_t stream) {
    const float* x  = (const float*)d_in[0];
    const float* wq = (const float*)d_in[1];
    const float* wk = (const float*)d_in[2];
    const float* wv = (const float*)d_in[3];
    const float* wo = (const float*)d_in[4];
    const float* fc = (const float*)d_in[5];
    const float* fs = (const float*)d_in[6];
    float* out = (float*)d_out;

    const int NX = 2048 * 4096;
    const int NQW = 4096 * 4096;
    const int NKW = 1024 * 4096;
    const int NKV = 2048 * 1024;

    u16* Q   = (u16*)d_ws;
    u16* Kc  = Q   + NX;
    u16* Vt  = Kc  + NKV;   // [1024 features][2048 seq]
    u16* Ao  = Vt  + NKV;
    u16* xb  = Ao  + NX;
    u16* wqb = xb  + NX;
    u16* wkb = wqb + NQW;
    u16* wvb = wkb + NKW;
    u16* wob = wvb + NKW;

    cvt_all<<<24576, 256, 0, stream>>>(x, wq, wk, wv, wo,
                                       xb, wqb, wkb, wvb, wob);
    qkv_proj4<<<256, 512, 0, stream>>>(xb, wqb, wkb, wvb, Q, Kc, Vt);
    rope_all<<<20480, 256, 0, stream>>>(Q, Kc, fc, fs);
    flash_attn<<<dim3(16, 32), 256, 0, stream>>>(Q, Kc, Vt, Ao);
    oproj8<<<256, 512, 0, stream>>>(Ao, wob, out);
}

// Round 6
// 487.232 us; speedup vs baseline: 1.0456x; 1.0456x over previous
//
#include <hip/hip_runtime.h>
#include <math.h>
#include <stdint.h>
#include <stddef.h>

// ---------------------------------------------------------------------------
// Attention layer for MI355X (gfx950). I/O fp32; internal bf16 MFMA pipeline.
//   cvt_all: x/wq/wk/wv/wo -> bf16 (single fused launch)
//   qkv_proj8: 256x256 8-phase counted-vmcnt GEMM (T2+T3+T4+T5), 192 blocks,
//       bijective XCD map, sched_barrier(0) phase fences (rule 18)
//   oproj8: 128x256 4-phase counted-vmcnt GEMM, 256 blocks, XCD map, fences
//   rope_all: RoPE(Q)+RoPE(K) fused
//   flash_attn: LDS-staged (async global_load_lds, double-buffered),
//               key-permuted S^T trick, causal, GQA rep=4, defer-max rescale
// Only mfma_f32_16x16x32_bf16 is used (HW-verified layouts m89/m97).
// ---------------------------------------------------------------------------

typedef __attribute__((ext_vector_type(8))) short bf16x8;
typedef __attribute__((ext_vector_type(4))) short bf16x4;
typedef __attribute__((ext_vector_type(4))) float f32x4;
typedef unsigned short u16;

#define NEG_BIG (-1.0e9f)
#define MFMA32(a, b, c) __builtin_amdgcn_mfma_f32_16x16x32_bf16(a, b, c, 0, 0, 0)
#define SFENCE() __builtin_amdgcn_sched_barrier(0)

__device__ __forceinline__ float bf2f(u16 b) {
    return __uint_as_float(((unsigned int)b) << 16);
}
__device__ __forceinline__ u16 f2bf(float f) {
    unsigned int u = __float_as_uint(f);
    u += 0x7fff + ((u >> 16) & 1);   // RNE
    return (u16)(u >> 16);
}
__device__ __forceinline__ void gld_lds16(short* lds, const u16* g) {
    __builtin_amdgcn_global_load_lds(
        (const __attribute__((address_space(1))) void*)g,
        (__attribute__((address_space(3))) void*)lds, 16, 0, 0);
}

// ---------------------------------------------------------------------------
// fused fp32 -> bf16 convert for all 5 tensors (one launch)
// blocks: x 4096 | wq 8192 | wk 2048 | wv 2048 | wo 8192  (2048 elem/block)
// ---------------------------------------------------------------------------
__global__ __launch_bounds__(256) void cvt_all(
    const float* __restrict__ x, const float* __restrict__ wq,
    const float* __restrict__ wk, const float* __restrict__ wv,
    const float* __restrict__ wo,
    u16* __restrict__ xb, u16* __restrict__ wqb, u16* __restrict__ wkb,
    u16* __restrict__ wvb, u16* __restrict__ wob) {
    const int b = blockIdx.x;
    const float* s; u16* d; int off;
    if (b < 4096)       { s = x;  d = xb;  off = b; }
    else if (b < 12288) { s = wq; d = wqb; off = b - 4096; }
    else if (b < 14336) { s = wk; d = wkb; off = b - 12288; }
    else if (b < 16384) { s = wv; d = wvb; off = b - 14336; }
    else                { s = wo; d = wob; off = b - 16384; }
    const int i = off * 2048 + threadIdx.x * 8;
    float4 a, c;
    __builtin_memcpy(&a, s + i, 16);
    __builtin_memcpy(&c, s + i + 4, 16);
    bf16x8 o;
    o[0] = (short)f2bf(a.x); o[1] = (short)f2bf(a.y);
    o[2] = (short)f2bf(a.z); o[3] = (short)f2bf(a.w);
    o[4] = (short)f2bf(c.x); o[5] = (short)f2bf(c.y);
    o[6] = (short)f2bf(c.z); o[7] = (short)f2bf(c.w);
    __builtin_memcpy(d + i, &o, 16);
}

// ---------------------------------------------------------------------------
// 8-phase counted-vmcnt GEMM: C = A[M,K] @ B[N,K]^T, bf16 in, fp32 accum.
// Tile BM x BN, BK=64, 512 threads (8 waves as 2M x 4N). MH = (BM/2)/64.
// Phase: ds_read frags -> stage one future half-tile -> SFENCE -> s_barrier
// -> lgkmcnt(0) -> SFENCE -> setprio(1) 16 MFMA setprio(0) -> SFENCE ->
// [counted vmcnt] -> s_barrier.  The sched_barrier(0) fences pin the phase
// regions against compiler reordering (rule 18: hipcc hoists register-only
// MFMA past inline-asm waits, dissolving the interleave).
//
// T2 bank swizzle (verified r4: conflicts 9.4M -> 0): read slot
// quad ^ ((row>>1)&3); inverse baked into global source slot
// cs = (t&3)^((t>>3)&3)  (LDS dest of global_load_lds stays linear).
//
// Stagger (earliest-dead-phase staging; counted vmcnt + barrier = collective
// guarantee):
//   MH=2: p0:b1.Ak1(JIT) p1:b1.Bk1 p2:b0.Ak0 p3:b0.Bk0 p4:b0.Ak1
//         p5:b0.Bk1 p6:b1.Ak0 p7:b1.Bk0;  vmcnt(4) at p3/p7 only.
//   MH=1: p0:b1.{A,B}k1(JIT) p1:b0.k0 p2:b0.k1 p3:b1.k0; vmcnt(6) each phase.
// Never vmcnt(0) in the main loop; final iteration peeled and drained.
// ---------------------------------------------------------------------------

#define G8_STGA(bf_, ks_, kt_)                                               \
    {                                                                        \
        _Pragma("unroll") for (int r_ = 0; r_ < RA; ++r_)                    \
            gld_lds16(Ad + (bf_) * AT + (ks_) * AH + r_ * 4096,              \
                      Ag + gK * r_ + (size_t)(kt_) * 64 + (ks_) * 32);       \
    }
#define G8_STGB(bf_, ks_, kt_)                                               \
    {                                                                        \
        _Pragma("unroll") for (int r_ = 0; r_ < RB; ++r_)                    \
            gld_lds16(Bd + (bf_) * BT + (ks_) * BH + r_ * 4096,              \
                      Bg + gK * r_ + (size_t)(kt_) * 64 + (ks_) * 32);       \
    }
#define G8_PHASE(bf_, ks_, mh_, RDB_, STAGE_, WAIT_)                         \
    {                                                                        \
        if (RDB_) {                                                          \
            _Pragma("unroll") for (int n_ = 0; n_ < 4; ++n_)                 \
                __builtin_memcpy(&bfr[n_], Bs + (bf_) * BT + (ks_) * BH +    \
                                               bbase + n_ * 512, 16);        \
        }                                                                    \
        _Pragma("unroll") for (int i_ = 0; i_ < 4; ++i_)                     \
            __builtin_memcpy(&af[i_], S + (bf_) * AT + (ks_) * AH + abase +  \
                                          ((mh_) * 64 + i_ * 16) * 32, 16);  \
        STAGE_;                                                              \
        SFENCE();                                                            \
        __builtin_amdgcn_s_barrier();                                        \
        asm volatile("s_waitcnt lgkmcnt(0)" ::: "memory");                   \
        SFENCE();                                                            \
        __builtin_amdgcn_s_setprio(1);                                       \
        _Pragma("unroll") for (int i_ = 0; i_ < 4; ++i_)                     \
            _Pragma("unroll") for (int n_ = 0; n_ < 4; ++n_)                 \
                acc[(mh_) * 4 + i_][n_] =                                    \
                    MFMA32(af[i_], bfr[n_], acc[(mh_) * 4 + i_][n_]);        \
        __builtin_amdgcn_s_setprio(0);                                       \
        SFENCE();                                                            \
        WAIT_;                                                               \
        __builtin_amdgcn_s_barrier();                                        \
    }

template <int BM, int BN, int MH, int OUT>
__device__ __forceinline__ void gemm8p(const u16* __restrict__ A,
                                       const u16* __restrict__ B,
                                       void* __restrict__ C,
                                       int mb, int nb, int N, int K,
                                       short* __restrict__ S) {
    constexpr int AT = BM * 64, BT = BN * 64;    // shorts per buffer tile
    constexpr int AH = BM * 32, BH = BN * 32;    // shorts per ks-half
    constexpr int RA = BM / 128, RB = BN / 128;  // gld rounds per half
    short* const Bs = S + 2 * AT;

    const int t = threadIdx.x;
    const int lane = t & 63, l15 = lane & 15, quad = lane >> 4;
    const int wid = t >> 6, wr = wid >> 2, wc = wid & 3;

    // staging: thread t, round r covers row (t>>2)+128r; LDS slot t&3 holds
    // global slot cs (inverse of the read swizzle)
    const int srow = t >> 2;
    const int cs = (t & 3) ^ ((t >> 3) & 3);
    const u16* const Ag = A + (size_t)(mb * BM + srow) * K + cs * 8;
    const u16* const Bg = B + (size_t)(nb * BN + srow) * K + cs * 8;
    short* const Ad = S + t * 8;
    short* const Bd = Bs + t * 8;
    const size_t gK = (size_t)128 * K;

    // ds-read bases (per-lane), T2-swizzled slot
    const int swz = (quad ^ ((l15 >> 1) & 3)) * 8;
    const int abase = (wr * (BM / 2) + l15) * 32 + swz;
    const int bbase = (wc * 64 + l15) * 32 + swz;

    f32x4 acc[MH * 4][4] = {};
    bf16x8 af[4], bfr[4];

    // ---- prologue: buf0 <- tile 0 (both halves), buf1.k0 <- tile 1 ----
    G8_STGA(0, 0, 0); G8_STGB(0, 0, 0);
    G8_STGA(0, 1, 0); G8_STGB(0, 1, 0);
    G8_STGA(1, 0, 1); G8_STGB(1, 0, 1);
    if constexpr (MH == 2) {
        asm volatile("s_waitcnt vmcnt(4)" ::: "memory");
    } else {
        asm volatile("s_waitcnt vmcnt(6)" ::: "memory");
    }
    __builtin_amdgcn_s_barrier();

    const int nIt = K >> 7;   // 2 K-tiles per iteration
    if constexpr (MH == 2) {
        for (int it = 0; it < nIt; ++it) {
            const int k0 = 2 * it, k1 = k0 + 1;
            const bool nl = (it < nIt - 1);
            G8_PHASE(0, 0, 0, true,  G8_STGA(1, 1, k1), );
            G8_PHASE(0, 0, 1, false, G8_STGB(1, 1, k1), );
            G8_PHASE(0, 1, 0, true,  if (nl) G8_STGA(0, 0, k0 + 2), );
            G8_PHASE(0, 1, 1, false, if (nl) G8_STGB(0, 0, k0 + 2),
                     if (nl) { asm volatile("s_waitcnt vmcnt(4)" ::: "memory"); }
                     else    { asm volatile("s_waitcnt vmcnt(0)" ::: "memory"); });
            G8_PHASE(1, 0, 0, true,  if (nl) G8_STGA(0, 1, k0 + 2), );
            G8_PHASE(1, 0, 1, false, if (nl) G8_STGB(0, 1, k0 + 2), );
            G8_PHASE(1, 1, 0, true,  if (nl) G8_STGA(1, 0, k1 + 2), );
            G8_PHASE(1, 1, 1, false, if (nl) G8_STGB(1, 0, k1 + 2),
                     if (nl) { asm volatile("s_waitcnt vmcnt(4)" ::: "memory"); });
        }
    } else {
        for (int it = 0; it < nIt - 1; ++it) {
            const int k0 = 2 * it, k1 = k0 + 1;
            G8_PHASE(0, 0, 0, true, { G8_STGA(1, 1, k1); G8_STGB(1, 1, k1); },
                     asm volatile("s_waitcnt vmcnt(6)" ::: "memory"));
            G8_PHASE(0, 1, 0, true, { G8_STGA(0, 0, k0 + 2); G8_STGB(0, 0, k0 + 2); },
                     asm volatile("s_waitcnt vmcnt(6)" ::: "memory"));
            G8_PHASE(1, 0, 0, true, { G8_STGA(0, 1, k0 + 2); G8_STGB(0, 1, k0 + 2); },
                     asm volatile("s_waitcnt vmcnt(6)" ::: "memory"));
            G8_PHASE(1, 1, 0, true, { G8_STGA(1, 0, k1 + 2); G8_STGB(1, 0, k1 + 2); },
                     asm volatile("s_waitcnt vmcnt(6)" ::: "memory"));
        }
        {   // final iteration, peeled: drain
            const int k1 = (K >> 6) - 1;
            G8_PHASE(0, 0, 0, true, { G8_STGA(1, 1, k1); G8_STGB(1, 1, k1); },
                     asm volatile("s_waitcnt vmcnt(6)" ::: "memory"));
            G8_PHASE(0, 1, 0, true, ,
                     asm volatile("s_waitcnt vmcnt(3)" ::: "memory"));
            G8_PHASE(1, 0, 0, true, ,
                     asm volatile("s_waitcnt vmcnt(0)" ::: "memory"));
            G8_PHASE(1, 1, 0, true, , );
        }
    }

    // ---- epilogue. C/D layout: col = l15, row = quad*4 + r ----
#pragma unroll
    for (int i8 = 0; i8 < MH * 4; ++i8) {
        const int rowb = mb * BM + wr * (BM / 2) + (i8 >> 2) * 64 +
                         (i8 & 3) * 16 + quad * 4;
#pragma unroll
        for (int j = 0; j < 4; ++j) {
            const int col = nb * BN + wc * 64 + j * 16 + l15;
            if (OUT == 2) {
                // transposed write: [col][seq], 4 consecutive rows -> 8B
                bf16x4 v;
#pragma unroll
                for (int r = 0; r < 4; ++r) v[r] = (short)f2bf(acc[i8][j][r]);
                __builtin_memcpy((u16*)C + (size_t)col * 2048 + rowb, &v, 8);
            } else if (OUT == 1) {
#pragma unroll
                for (int r = 0; r < 4; ++r)
                    ((float*)C)[(size_t)(rowb + r) * N + col] = acc[i8][j][r];
            } else {
#pragma unroll
                for (int r = 0; r < 4; ++r)
                    ((u16*)C)[(size_t)(rowb + r) * N + col] =
                        f2bf(acc[i8][j][r]);
            }
        }
    }
}

__global__ __launch_bounds__(512, 2) void qkv_proj8(
    const u16* __restrict__ x,
    const u16* __restrict__ wq, const u16* __restrict__ wk,
    const u16* __restrict__ wv,
    u16* __restrict__ Q, u16* __restrict__ Kc, u16* __restrict__ Vt) {
    __shared__ __align__(16) short S[65536];   // 128 KiB
    // bijective XCD map over 192 = 8 x 24: each XCD owns 3 consecutive
    // B-panels (y) across all mb -> B panel L2 reuse within an XCD.
    const int lid = blockIdx.x;
    const int swzb = (lid & 7) * 24 + (lid >> 3);
    const int mb = swzb & 7, y = swzb >> 3;
    if (y < 16)
        gemm8p<256, 256, 2, 0>(x, wq, Q, mb, y, 4096, 4096, S);
    else if (y < 20)
        gemm8p<256, 256, 2, 0>(x, wk, Kc, mb, y - 16, 1024, 4096, S);
    else
        gemm8p<256, 256, 2, 2>(x, wv, Vt, mb, y - 20, 1024, 4096, S);
}

__global__ __launch_bounds__(512, 2) void oproj8(
    const u16* __restrict__ A, const u16* __restrict__ wo,
    float* __restrict__ out) {
    __shared__ __align__(16) short S[49152];   // 96 KiB
    const int lid = blockIdx.x;
    const int logical = (lid & 7) * 32 + (lid >> 3);
    const int mb = logical & 15, nb = logical >> 4;
    gemm8p<128, 256, 1, 1>(A, wo, out, mb, nb, 4096, 4096, S);
}

// ---------------------------------------------------------------------------
// fused RoPE: Q (32 heads) + Kc (8 heads) in one launch.
// ---------------------------------------------------------------------------
__global__ __launch_bounds__(256) void rope_all(
    u16* __restrict__ Q, u16* __restrict__ Kc,
    const float* __restrict__ cosb, const float* __restrict__ sinb) {
    const int idx = blockIdx.x * blockDim.x + threadIdx.x;
    const int i = idx & 63;
    const int hh = (idx >> 6) % 40;
    const int s = (idx >> 6) / 40;
    u16* p;
    if (hh < 32)
        p = Q + (size_t)s * 4096 + hh * 128 + 2 * i;
    else
        p = Kc + (size_t)s * 1024 + (hh - 32) * 128 + 2 * i;
    const float x0 = bf2f(p[0]), x1 = bf2f(p[1]);
    const float c = cosb[s * 64 + i], sn = sinb[s * 64 + i];
    p[0] = f2bf(x0 * c - x1 * sn);
    p[1] = f2bf(x0 * sn + x1 * c);
}

// ---------------------------------------------------------------------------
// Flash attention, LDS-staged (2-phase global_load_lds pipeline, dbuf).
// K tile [32 keys][128 dims] XOR-swizzled 16B slots (2-way, free);
// V tile [128 feats][32 keys] with T2 slot swizzle quad ^ ((row>>1)&3).
// Key-permuted S^T trick; online softmax with defer-max THR=8.
// ---------------------------------------------------------------------------
__device__ __forceinline__ int kswz(int row, int cs) {
    int f = (row & 3) | ((row & 8) >> 1);
    return row * 128 + ((cs ^ f) << 3);
}

template <bool MASKED>
__device__ __forceinline__ void fa_step_lds(
    const short* __restrict__ Kl, const short* __restrict__ Vl,
    int kb, int q0, int l15, int quad,
    const int (&koff)[8], const int (&voff)[8],
    const bf16x8 (&qf)[4], f32x4 (&o)[8], float& m, float& l) {
    const float scale = 0.08838834764831845f;  // 1/sqrt(128)

    // K frags from LDS (swizzled) + S^T = K.Q^T
    bf16x8 kf[8];
#pragma unroll
    for (int i = 0; i < 8; ++i) __builtin_memcpy(&kf[i], Kl + koff[i], 16);
    f32x4 s0 = {0, 0, 0, 0}, s1 = {0, 0, 0, 0};
#pragma unroll
    for (int c = 0; c < 4; ++c) {
        s0 = MFMA32(kf[c], qf[c], s0);
        s1 = MFMA32(kf[4 + c], qf[c], s1);
    }

    // V frags early: ds_read latency hides under softmax
    bf16x8 vf[8];
#pragma unroll
    for (int n = 0; n < 8; ++n) __builtin_memcpy(&vf[n], Vl + voff[n], 16);

    // scale + causal mask. Lane (quad,l15): s0[r] = key kb+8*quad+r,
    // s1[r] = key kb+8*quad+4+r, q column = l15.
    float sv0[4], sv1[4];
    const int q = q0 + l15;
#pragma unroll
    for (int r = 0; r < 4; ++r) {
        sv0[r] = s0[r] * scale;
        sv1[r] = s1[r] * scale;
        if (MASKED) {
            if (kb + 8 * quad + r > q) sv0[r] = NEG_BIG;
            if (kb + 8 * quad + 4 + r > q) sv1[r] = NEG_BIG;
        }
    }

    // online softmax: all 32 keys of q-col l15 spread across quads
    float mx = fmaxf(fmaxf(fmaxf(sv0[0], sv0[1]), fmaxf(sv0[2], sv0[3])),
                     fmaxf(fmaxf(sv1[0], sv1[1]), fmaxf(sv1[2], sv1[3])));
    mx = fmaxf(mx, __shfl_xor(mx, 16));
    mx = fmaxf(mx, __shfl_xor(mx, 32));

    // defer-max: only rescale O when the max grew past the threshold
    float alpha = 1.0f;
    if (!__all(mx <= m + 8.0f)) {
        float mnew = fmaxf(m, mx);
        alpha = __expf(m - mnew);
        float aO[4];
#pragma unroll
        for (int r = 0; r < 4; ++r) aO[r] = __shfl(alpha, quad * 20 + r);
#pragma unroll
        for (int n = 0; n < 8; ++n)
#pragma unroll
            for (int r = 0; r < 4; ++r) o[n][r] *= aO[r];
        m = mnew;
    }

    float p0[4], p1[4], sum = 0.f;
#pragma unroll
    for (int r = 0; r < 4; ++r) {
        p0[r] = __expf(sv0[r] - m);
        p1[r] = __expf(sv1[r] - m);
        sum += p0[r] + p1[r];
    }
    sum += __shfl_xor(sum, 16);
    sum += __shfl_xor(sum, 32);
    l = l * alpha + sum;

    // pack P into the 16x16x32 A-frag: element j = key 8*quad+j (zero move)
    bf16x8 pa;
#pragma unroll
    for (int r = 0; r < 4; ++r) {
        pa[r] = (short)f2bf(p0[r]);
        pa[4 + r] = (short)f2bf(p1[r]);
    }

    // O += P.V
#pragma unroll
    for (int n = 0; n < 8; ++n) o[n] = MFMA32(pa, vf[n], o[n]);
}

__device__ __forceinline__ void fa_task(
    const u16* __restrict__ Q, const u16* __restrict__ Kc,
    const u16* __restrict__ Vt, u16* __restrict__ O,
    short* __restrict__ Kl0, short* __restrict__ Vl0,
    int q0, int nbt, int h, int kvh, int t) {
    const int lane = t & 63;
    const int l15 = lane & 15, quad = lane >> 4;

    // Q B-frags (n=q=l15, k=d chunks)
    bf16x8 qf[4];
    const u16* qp = Q + (size_t)(q0 + l15) * 4096 + h * 128 + quad * 8;
#pragma unroll
    for (int c = 0; c < 4; ++c) __builtin_memcpy(&qf[c], qp + c * 32, 16);

    // ---- staging addresses (per-thread constants) ----
    const u16* ksrc[2]; short* kdst[2];
    const u16* vsrc[2]; short* vdst[2];
#pragma unroll
    for (int r = 0; r < 2; ++r) {
        int row = (t >> 4) + 16 * r;
        int slot = t & 15;
        int f = (row & 3) | ((row & 8) >> 1);
        int cks = slot ^ f;
        ksrc[r] = Kc + (size_t)row * 1024 + kvh * 128 + cks * 8;
        kdst[r] = Kl0 + (t + 256 * r) * 8;
        int rowv = (t >> 2) + 64 * r;
        int csv = (t & 3) ^ ((t >> 3) & 3);   // inverse of V read swizzle
        vsrc[r] = Vt + (size_t)(kvh * 128 + rowv) * 2048 + csv * 8;
        vdst[r] = Vl0 + (t + 256 * r) * 8;
    }

    // ---- LDS read offsets (per-lane constants) ----
    const int rk0 = 8 * (l15 >> 2) + (l15 & 3);   // key-permuted row (s0)
    int koff[8], voff[8];
#pragma unroll
    for (int c = 0; c < 4; ++c) {
        koff[c] = kswz(rk0, quad + c * 4);
        koff[4 + c] = kswz(rk0 + 4, quad + c * 4);
    }
    const int vswz = (quad ^ ((l15 >> 1) & 3)) * 8;
#pragma unroll
    for (int n = 0; n < 8; ++n) voff[n] = (n * 16 + l15) * 32 + vswz;

    f32x4 o[8] = {};
    float m = NEG_BIG, l = 0.f;
    const int my_nb = (q0 + 47) / 32;   // my causal key-block count (<= nbt)

    // ---- prologue: stage block 0 into buffer 0 ----
    {
        gld_lds16(kdst[0], ksrc[0]);
        gld_lds16(kdst[1], ksrc[1]);
        gld_lds16(vdst[0], vsrc[0]);
        gld_lds16(vdst[1], vsrc[1]);
    }
    __syncthreads();

    for (int ib = 0; ib < nbt; ++ib) {
        if (ib + 1 < nbt) {   // stage next block into the other buffer
            int kb = (ib + 1) * 32;
            int bo = ((ib + 1) & 1) * 4096;
            gld_lds16(kdst[0] + bo, ksrc[0] + (size_t)kb * 1024);
            gld_lds16(kdst[1] + bo, ksrc[1] + (size_t)kb * 1024);
            gld_lds16(vdst[0] + bo, vsrc[0] + kb);
            gld_lds16(vdst[1] + bo, vsrc[1] + kb);
        }
        if (ib < my_nb) {   // wave-uniform predicate
            const short* Kl = Kl0 + (ib & 1) * 4096;
            const short* Vl = Vl0 + (ib & 1) * 4096;
            if (ib == my_nb - 1)
                fa_step_lds<true>(Kl, Vl, ib * 32, q0, l15, quad, koff, voff,
                                  qf, o, m, l);
            else
                fa_step_lds<false>(Kl, Vl, ib * 32, q0, l15, quad, koff, voff,
                                   qf, o, m, l);
        }
        __syncthreads();
    }

    // epilogue: O rows are q=quad*4+r; fetch l from q=l15 lanes
    float inv[4];
#pragma unroll
    for (int r = 0; r < 4; ++r) inv[r] = 1.f / __shfl(l, quad * 20 + r);
#pragma unroll
    for (int n = 0; n < 8; ++n)
#pragma unroll
        for (int r = 0; r < 4; ++r) {
            int row = q0 + quad * 4 + r;
            O[(size_t)row * 4096 + h * 128 + n * 16 + l15] =
                f2bf(o[n][r] * inv[r]);
        }
}

__global__ __launch_bounds__(256) void flash_attn(
    const u16* __restrict__ Q, const u16* __restrict__ Kc,
    const u16* __restrict__ Vt, u16* __restrict__ O) {
    __shared__ __align__(16) short Kl[2 * 32 * 128];
    __shared__ __align__(16) short Vl[2 * 128 * 32];
    const int pp = blockIdx.x;   // 0..15  (q-tile pair: pp and 31-pp)
    const int h = blockIdx.y;    // 0..31
    const int kvh = h >> 2;
    const int t = threadIdx.x, wave = t >> 6;
    fa_task(Q, Kc, Vt, O, Kl, Vl, pp * 64 + wave * 16, 2 * pp + 2, h, kvh, t);
    const int tb = 31 - pp;
    fa_task(Q, Kc, Vt, O, Kl, Vl, tb * 64 + (3 - wave) * 16, 2 * tb + 2, h,
            kvh, t);
}

// ---------------------------------------------------------------------------
extern "C" void kernel_launch(void* const* d_in, const int* in_sizes, int n_in,
                              void* d_out, int out_size, void* d_ws,
                              size_t ws_size, hipStream_t stream) {
    const float* x  = (const float*)d_in[0];
    const float* wq = (const float*)d_in[1];
    const float* wk = (const float*)d_in[2];
    const float* wv = (const float*)d_in[3];
    const float* wo = (const float*)d_in[4];
    const float* fc = (const float*)d_in[5];
    const float* fs = (const float*)d_in[6];
    float* out = (float*)d_out;

    const int NX = 2048 * 4096;
    const int NQW = 4096 * 4096;
    const int NKW = 1024 * 4096;
    const int NKV = 2048 * 1024;

    u16* Q   = (u16*)d_ws;
    u16* Kc  = Q   + NX;
    u16* Vt  = Kc  + NKV;   // [1024 features][2048 seq]
    u16* Ao  = Vt  + NKV;
    u16* xb  = Ao  + NX;
    u16* wqb = xb  + NX;
    u16* wkb = wqb + NQW;
    u16* wvb = wkb + NKW;
    u16* wob = wvb + NKW;

    cvt_all<<<24576, 256, 0, stream>>>(x, wq, wk, wv, wo,
                                       xb, wqb, wkb, wvb, wob);
    qkv_proj8<<<192, 512, 0, stream>>>(xb, wqb, wkb, wvb, Q, Kc, Vt);
    rope_all<<<20480, 256, 0, stream>>>(Q, Kc, fc, fs);
    flash_attn<<<dim3(16, 32), 256, 0, stream>>>(Q, Kc, Vt, Ao);
    oproj8<<<256, 512, 0, stream>>>(Ao, wob, out);
}